// Round 6
// baseline (449.194 us; speedup 1.0000x reference)
//
#include <hip/hip_runtime.h>
#include <hip/hip_bf16.h>

// GraphAttentionLayer: B=4, N=4096, F=64
// h = inp@W; lh = lrelu(h,.2); fsrc = lh@a[:64]; fdst = lh@a[64:]
// dj = 0.8*adj[i][j] + 0.2*(fsrc[i]+fdst[j]); E = dj>0 ? exp(dj) : 0  (dj<=~3.3, no max needed)
// s[j] = sum_i E[i][j];  out[i][o] = relu( sum_j E[i][j] * (h[j][o]/s[j]) )
// R6: E is NEVER materialized — pass 2 recomputes it per MFMA A-fragment.
// Zero dirty-L3 bulk data: adj read twice (2nd pass L3-hot), only pm/part/out written.

#define Bn 4
#define Nn 4096
#define KS 4    // K-split in attnmm
#define IC 64   // i-chunks in colsum

typedef _Float16 half8 __attribute__((ext_vector_type(8)));
typedef float f32x4 __attribute__((ext_vector_type(4)));
typedef float f4v __attribute__((ext_vector_type(4)));

__global__ __launch_bounds__(256) void k_prep(
    const float* __restrict__ inp, const float* __restrict__ W,
    const float* __restrict__ a, float* __restrict__ h,
    float* __restrict__ fsrc, float* __restrict__ fdst) {
  __shared__ float Ws[64 * 64];
  __shared__ float as[128];
  __shared__ float xs[4][64];
  const int t = threadIdx.x;
  for (int k = t; k < 4096; k += 256) Ws[k] = W[k];
  if (t < 128) as[t] = a[t];
  const int w = t >> 6;
  const int o = t & 63;
  const int row = blockIdx.x * 4 + w;
  xs[w][o] = inp[(size_t)row * 64 + o];
  __syncthreads();
  float acc = 0.f;
  const float* xr = xs[w];
#pragma unroll
  for (int f = 0; f < 64; ++f) acc += xr[f] * Ws[f * 64 + o];
  h[(size_t)row * 64 + o] = acc;
  float lh = acc > 0.f ? acc : 0.2f * acc;
  float vs = lh * as[o];
  float vd = lh * as[64 + o];
#pragma unroll
  for (int off = 32; off > 0; off >>= 1) {
    vs += __shfl_down(vs, off);
    vd += __shfl_down(vd, off);
  }
  if (o == 0) { fsrc[row] = vs; fdst[row] = vd; }
}

// Pass 1: column partial sums of masked exp. NO E write, NO nt (we want adj
// resident in L3 for pass 2). grid (jb=4, ic=64, b=4) = 1024 blocks.
__global__ __launch_bounds__(256) void k_colsum(
    const float* __restrict__ adj, const float* __restrict__ fsrc,
    const float* __restrict__ fdst, float* __restrict__ pm) {
  const int t = threadIdx.x;
  const int jb = blockIdx.x, ic = blockIdx.y, b = blockIdx.z;
  const int j = jb * 1024 + t * 4;
  const int i0 = ic * 64;
  __shared__ float fss[64];
  if (t < 64) fss[t] = fsrc[b * Nn + i0 + t];
  __syncthreads();
  const float4 fd = *(const float4*)&fdst[b * Nn + j];
  const float fd0 = 0.2f * fd.x, fd1 = 0.2f * fd.y, fd2 = 0.2f * fd.z, fd3 = 0.2f * fd.w;
  const f4v* ap = (const f4v*)(adj + ((size_t)(b * Nn + i0)) * Nn + j);
  float s0 = 0.f, s1 = 0.f, s2 = 0.f, s3 = 0.f;
#pragma unroll 4
  for (int ii = 0; ii < 64; ++ii) {
    f4v v = ap[(size_t)ii * 1024];
    float fi = 0.2f * fss[ii];
    float d0 = 0.8f * v.x + (fi + fd0);
    float d1 = 0.8f * v.y + (fi + fd1);
    float d2 = 0.8f * v.z + (fi + fd2);
    float d3 = 0.8f * v.w + (fi + fd3);
    s0 += d0 > 0.f ? __expf(d0) : 0.f;
    s1 += d1 > 0.f ? __expf(d1) : 0.f;
    s2 += d2 > 0.f ? __expf(d2) : 0.f;
    s3 += d3 > 0.f ? __expf(d3) : 0.f;
  }
  float4 sv; sv.x = s0; sv.y = s1; sv.z = s2; sv.w = s3;
  *(float4*)&pm[((size_t)(ic * Bn + b)) * Nn + j] = sv;
}

// Reduce pm over ic, then hT[b][o][j] = fp16( h[b][j][o] / s[j] ).
// grid (jt=64, b=4), block 256.
__global__ __launch_bounds__(256) void k_hscale(
    const float* __restrict__ h, const float* __restrict__ pm,
    _Float16* __restrict__ hT) {
  const int t = threadIdx.x;
  const int jt = blockIdx.x, b = blockIdx.y;
  __shared__ _Float16 hl[64][72];
  __shared__ float sis[64];
  if (t < 64) {
    const int j = jt * 64 + t;
    float sv = 0.f;
#pragma unroll 8
    for (int ic = 0; ic < IC; ++ic) sv += pm[((size_t)(ic * Bn + b)) * Nn + j];
    sis[t] = sv > 0.f ? 1.0f / sv : 0.f;   // all-masked column contributes 0
  }
  __syncthreads();
#pragma unroll
  for (int r = 0; r < 4; ++r) {
    const int jl = r * 16 + (t >> 4);
    const int j = jt * 64 + jl;
    const int o4 = (t & 15) * 4;
    float si = sis[jl];
    float4 hv = *(const float4*)&h[((size_t)(b * Nn + j)) * 64 + o4];
    hl[o4 + 0][jl] = (_Float16)(hv.x * si);
    hl[o4 + 1][jl] = (_Float16)(hv.y * si);
    hl[o4 + 2][jl] = (_Float16)(hv.z * si);
    hl[o4 + 3][jl] = (_Float16)(hv.w * si);
  }
  __syncthreads();
#pragma unroll
  for (int r = 0; r < 2; ++r) {
    const int o = r * 32 + (t >> 3);
    const int ch = t & 7;
    half8 v = *(half8*)&hl[o][ch * 8];
    *(half8*)&hT[((size_t)(b * 64 + o)) * 4096 + jt * 64 + ch * 8] = v;
  }
}

// Pass 2: part = E @ hT with E recomputed per A-fragment from adj (nt, L3-hot).
// grid (ks=4, ib=64, b=4) = 1024 blocks (4/CU), block 256 (4 waves).
// Block: 64 i x 64 o, K-slice 1024, LDS chunk 128 k (17.4 KB).
// A-frag layout (16x16x32): lane holds A[m=lane&15][k=(lane>>4)*8+j] — the 8
// adj floats per lane land exactly in the fragment slots.
__global__ __launch_bounds__(256, 4) void k_attnmm(
    const float* __restrict__ adj, const _Float16* __restrict__ hT,
    const float* __restrict__ fsrc, const float* __restrict__ fdst,
    float* __restrict__ part) {
  const int t = threadIdx.x;
  const int ks = blockIdx.x;
  const int ib = blockIdx.y;
  const int b = blockIdx.z;
  const int i0 = ib * 64;
  const int kbase = ks * 1024;
  const int w = t >> 6;
  const int lane = t & 63;
  const int m = lane & 15;
  const int q = lane >> 4;

  __shared__ _Float16 hs[64][136];   // [o][k-chunk 128], stride 272 B (16B-aligned)

  f32x4 acc[4];
#pragma unroll
  for (int nt = 0; nt < 4; ++nt)
#pragma unroll
    for (int r = 0; r < 4; ++r) acc[nt][r] = 0.f;

  const int ai = i0 + w * 16 + m;
  const float fs2 = 0.2f * fsrc[b * Nn + ai];
  const float* arow = adj + ((size_t)(b * Nn + ai)) * Nn + kbase;
  const float* fdr = fdst + b * Nn + kbase;

  const int so = t >> 2;             // hT staging: 4 threads per o-row
  const int sk = (t & 3) * 32;       // each covers 32 k
  const _Float16* hTrow = hT + ((size_t)(b * 64 + so)) * Nn + kbase + sk;

  for (int ch = 0; ch < 8; ++ch) {
    const int k0 = ch * 128;
    __syncthreads();
#pragma unroll
    for (int qq = 0; qq < 4; ++qq) {
      half8 v = *(const half8*)(hTrow + k0 + qq * 8);
      *(half8*)&hs[so][sk + qq * 8] = v;
    }
    __syncthreads();
#pragma unroll
    for (int kt = 0; kt < 4; ++kt) {
      const int kc = k0 + kt * 32 + q * 8;
      f4v v0 = __builtin_nontemporal_load((const f4v*)(arow + kc));
      f4v v1 = __builtin_nontemporal_load((const f4v*)(arow + kc + 4));
      float4 fdA = *(const float4*)(fdr + kc);       // broadcast within q-group
      float4 fdB = *(const float4*)(fdr + kc + 4);
      float d0 = 0.8f * v0.x + (fs2 + 0.2f * fdA.x);
      float d1 = 0.8f * v0.y + (fs2 + 0.2f * fdA.y);
      float d2 = 0.8f * v0.z + (fs2 + 0.2f * fdA.z);
      float d3 = 0.8f * v0.w + (fs2 + 0.2f * fdA.w);
      float d4 = 0.8f * v1.x + (fs2 + 0.2f * fdB.x);
      float d5 = 0.8f * v1.y + (fs2 + 0.2f * fdB.y);
      float d6 = 0.8f * v1.z + (fs2 + 0.2f * fdB.z);
      float d7 = 0.8f * v1.w + (fs2 + 0.2f * fdB.w);
      half8 af;
      af[0] = (_Float16)(d0 > 0.f ? __expf(d0) : 0.f);
      af[1] = (_Float16)(d1 > 0.f ? __expf(d1) : 0.f);
      af[2] = (_Float16)(d2 > 0.f ? __expf(d2) : 0.f);
      af[3] = (_Float16)(d3 > 0.f ? __expf(d3) : 0.f);
      af[4] = (_Float16)(d4 > 0.f ? __expf(d4) : 0.f);
      af[5] = (_Float16)(d5 > 0.f ? __expf(d5) : 0.f);
      af[6] = (_Float16)(d6 > 0.f ? __expf(d6) : 0.f);
      af[7] = (_Float16)(d7 > 0.f ? __expf(d7) : 0.f);
#pragma unroll
      for (int nt = 0; nt < 4; ++nt) {
        half8 bf = *(const half8*)&hs[nt * 16 + m][kt * 32 + q * 8];
        acc[nt] = __builtin_amdgcn_mfma_f32_16x16x32_f16(af, bf, acc[nt], 0, 0, 0);
      }
    }
  }
  // C/D layout: col = lane&15 (o), row = (lane>>4)*4 + r (i)
#pragma unroll
  for (int nt = 0; nt < 4; ++nt)
#pragma unroll
    for (int r = 0; r < 4; ++r) {
      const int i = i0 + w * 16 + q * 4 + r;
      const int o = nt * 16 + m;
      part[(((size_t)ks * Bn + b) * Nn + i) * 64 + o] = acc[nt][r];
    }
}

__global__ __launch_bounds__(256) void k_final(
    const float* __restrict__ part, float* __restrict__ out) {
  const int e = blockIdx.x * 256 + threadIdx.x;
  const f4v* p4 = (const f4v*)part;
  f4v sv = __builtin_nontemporal_load(p4 + e);
  const size_t stride = (size_t)Bn * Nn * 64 / 4;
#pragma unroll
  for (int ks = 1; ks < KS; ++ks) {
    f4v v = __builtin_nontemporal_load(p4 + (size_t)ks * stride + e);
    sv.x += v.x; sv.y += v.y; sv.z += v.z; sv.w += v.w;
  }
  float4 r;
  r.x = fmaxf(sv.x, 0.f); r.y = fmaxf(sv.y, 0.f);
  r.z = fmaxf(sv.z, 0.f); r.w = fmaxf(sv.w, 0.f);
  ((float4*)out)[e] = r;
}

extern "C" void kernel_launch(void* const* d_in, const int* in_sizes, int n_in,
                              void* d_out, int out_size, void* d_ws, size_t ws_size,
                              hipStream_t stream) {
  const float* inp = (const float*)d_in[0];   // [4,4096,64]
  const float* adj = (const float*)d_in[1];   // [4,4096,4096]
  const float* W   = (const float*)d_in[2];   // [64,64]
  const float* a   = (const float*)d_in[3];   // [128,1]
  float* out = (float*)d_out;                 // [4,4096,64]

  float* ws   = (float*)d_ws;
  float* h    = ws;                           // 1,048,576 f32 (4 MB)
  float* fsrc = h + 1048576;                  // 16,384
  float* fdst = fsrc + 16384;                 // 16,384
  float* pm   = fdst + 16384;                 // IC*Bn*Nn f32 (4 MB)
  float* part = pm + (size_t)IC * Bn * Nn;    // KS*Bn*Nn*64 f32 (16 MB)
  _Float16* hT = (_Float16*)(part + (size_t)KS * Bn * Nn * 64);  // 2 MB

  k_prep<<<Bn * Nn / 4, 256, 0, stream>>>(inp, W, a, h, fsrc, fdst);
  k_colsum<<<dim3(4, IC, Bn), 256, 0, stream>>>(adj, fsrc, fdst, pm);
  k_hscale<<<dim3(64, Bn), 256, 0, stream>>>(h, pm, hT);
  k_attnmm<<<dim3(KS, 64, Bn), 256, 0, stream>>>(adj, hT, fsrc, fdst, part);
  k_final<<<Bn * Nn * 64 / 4 / 256, 256, 0, stream>>>(part, out);
}